// Round 1
// baseline (589.174 us; speedup 1.0000x reference)
//
#include <hip/hip_runtime.h>

// EdgeBlock v3: out[E,128] = concat(edges, nodes[recv], nodes[send]) @ W.T + b
// Round-3 restructure (latency-bound fix):
//  v2 was all-pipes-idle (Mfma 9%, VALU 8%, HBM 30%, occ 40%): 12x per-block
//  __syncthreads each drained vmcnt(0) with only 1-chunk prefetch -> exposed
//  full gather latency 12x/block, and acc[4][4]=64 AGPR capped 4 blocks/CU.
//  v3: full-K single-stage LDS (BM=32, K=384 -> 24 KB), ONE barrier per block.
//  All loads issued up front (~12 outstanding vmem/lane), wave tile 32x32
//  (acc=16 AGPR), launch_bounds(256,6) -> 6 blocks/CU target.
//  B-fragments stream from L2 (W bf16 = 98 KB, L2-resident), 2-deep prefetch.
//  LDS geometry (rows of 32 bf16, 16B-block XOR swizzle by (row>>1)&3) is
//  carried over verbatim from the verified v2 kernel.

#define BM  128   // fallback tile
#define BM3 32    // v3 tile
#define NCH 12

typedef __attribute__((ext_vector_type(8))) short bf16x8;
typedef __attribute__((ext_vector_type(4))) float floatx4;
typedef __attribute__((ext_vector_type(4))) unsigned int uint4v;

#define GLOAD_LDS16(g, l) __builtin_amdgcn_global_load_lds(                    \
    (const __attribute__((address_space(1))) unsigned int*)(g),                \
    (__attribute__((address_space(3))) unsigned int*)(l), 16, 0, 0)

static __device__ __forceinline__ unsigned int pack_bf16x2(float lo, float hi) {
    unsigned int a = __builtin_bit_cast(unsigned int, lo);
    unsigned int b = __builtin_bit_cast(unsigned int, hi);
    a += 0x7fffu + ((a >> 16) & 1u);   // RNE
    b += 0x7fffu + ((b >> 16) & 1u);
    return (a >> 16) | (b & 0xffff0000u);
}

// ---------- pre-pass: fp32 -> bf16 (float4 -> 8B) ----------
__global__ void cvt_bf16(const float* __restrict__ src, unsigned int* __restrict__ dst, int n4) {
    int i = blockIdx.x * blockDim.x + threadIdx.x;
    if (i < n4) {
        float4 v = ((const float4*)src)[i];
        uint2 p;
        p.x = pack_bf16x2(v.x, v.y);
        p.y = pack_bf16x2(v.z, v.w);
        ((uint2*)dst)[i] = p;
    }
}

// ---------- main GEMM v3: single-stage, single-barrier ----------
__global__ __launch_bounds__(256, 6)
void edge_gemm_v3(const float* __restrict__ edges,
                  const int*   __restrict__ recv,
                  const int*   __restrict__ send,
                  const unsigned short* __restrict__ nodes_bf,
                  const unsigned short* __restrict__ w_bf,
                  const float* __restrict__ bias,
                  float*       __restrict__ out,
                  int E)
{
    // 12 k-chunks x [32 rows x 32 bf16], 24 KB total, single use (no dbuf).
    // Chunk c: c<4 edges, 4..7 recv nodes, 8..11 send nodes.
    // Within a row, 16B block b holds source block b ^ ((row>>1)&3).
    __shared__ __align__(16) unsigned short As[NCH][BM3 * 32];

    const int tid  = threadIdx.x;
    const int wave = tid >> 6, lane = tid & 63;
    const int quad = lane >> 4, l16 = lane & 15;
    const int wn = wave * 32;                 // wave's 32 output cols
    const long e0 = (long)blockIdx.x * BM3;

    // --- node-gather: wave<2 stages recv rows [(wave&1)*16,+16), wave>=2 send ---
    const int rl   = lane >> 2;                      // row within 16-row group
    const int sblk = (lane & 3) ^ ((lane >> 3) & 3); // swizzled source 16B-block
    long er = e0 + (wave & 1) * 16 + rl; if (er > (long)E - 1) er = (long)E - 1;
    const int* idxp = (wave < 2) ? recv : send;
    const unsigned short* gp = nodes_bf + (long)idxp[er] * 128 + sblk * 8;
    const int cbase = (wave < 2) ? 4 : 8;

    // --- edge staging: thread t -> row t>>3, 4 floats per k-chunk (coalesced) ---
    const int erow = tid >> 3, ep = tid & 7;
    long ee = e0 + erow; if (ee > (long)E - 1) ee = (long)E - 1;
    const float* eptr = edges + ee * 128L + ep * 4;
    const int ephys = (((ep >> 1) ^ ((erow >> 1) & 3)) * 8) + (ep & 1) * 4; // ushort off

    // ---- issue ALL global traffic up front (deep MLP, one drain at barrier) ----
    float4 ev[4];
    #pragma unroll
    for (int i = 0; i < 4; ++i) ev[i] = *(const float4*)(eptr + i * 32);
    #pragma unroll
    for (int i = 0; i < 4; ++i)
        GLOAD_LDS16(gp + i * 32, &As[cbase + i][(wave & 1) * 512]);

    auto loadB = [&](int c, bf16x8* b) {
        #pragma unroll
        for (int ni = 0; ni < 2; ++ni)
            b[ni] = *(const bf16x8*)(w_bf + (long)(wn + ni * 16 + l16) * 384 + c * 32 + quad * 8);
    };

    bf16x8 bcur[2], bnxt[2];
    loadB(0, bcur);
    loadB(1, bnxt);

    float bv[2];
    #pragma unroll
    for (int ni = 0; ni < 2; ++ni) bv[ni] = bias[wn + ni * 16 + l16];

    // convert + LDS-write edges (write pattern is bank-conflict-free)
    #pragma unroll
    for (int i = 0; i < 4; ++i) {
        uint2 pw;
        pw.x = pack_bf16x2(ev[i].x, ev[i].y);
        pw.y = pack_bf16x2(ev[i].z, ev[i].w);
        *(uint2*)&As[i][erow * 32 + ephys] = pw;
    }

    __syncthreads();   // the ONLY barrier: drains gathers + edge writes once

    auto readA = [&](int c, bf16x8* a) {
        #pragma unroll
        for (int mi = 0; mi < 2; ++mi)
            a[mi] = *(const bf16x8*)&As[c][(mi * 16 + l16) * 32 +
                                           ((quad ^ ((l16 >> 1) & 3)) * 8)];
    };

    floatx4 acc[2][2] = {};
    bf16x8 acur[2];
    readA(0, acur);

    #pragma unroll
    for (int ks = 0; ks < NCH; ++ks) {
        bf16x8 an[2], bn[2];
        if (ks + 2 < NCH) loadB(ks + 2, bn);   // 2-deep B prefetch (L2 latency)
        if (ks + 1 < NCH) readA(ks + 1, an);   // 1-deep A prefetch (LDS)
        #pragma unroll
        for (int mi = 0; mi < 2; ++mi)
            #pragma unroll
            for (int ni = 0; ni < 2; ++ni)
                acc[mi][ni] = __builtin_amdgcn_mfma_f32_16x16x32_bf16(
                    acur[mi], bcur[ni], acc[mi][ni], 0, 0, 0);
        #pragma unroll
        for (int i = 0; i < 2; ++i) {
            if (ks + 1 < NCH) acur[i] = an[i];
            bcur[i] = bnxt[i];
            if (ks + 2 < NCH) bnxt[i] = bn[i];
        }
    }

    // epilogue: C/D layout col = lane&15, row = quad*4 + reg
    #pragma unroll
    for (int mi = 0; mi < 2; ++mi) {
        #pragma unroll
        for (int r = 0; r < 4; ++r) {
            long row = e0 + mi * 16 + quad * 4 + r;
            if (row < (long)E) {
                float* orow = out + row * 128L + wn + l16;
                orow[0]  = acc[mi][0][r] + bv[0];
                orow[16] = acc[mi][1][r] + bv[1];
            }
        }
    }
}

// ---------- fallback (round-1 kernel, used only if ws too small) ----------
#define SA 40
typedef __attribute__((ext_vector_type(8))) short bf16x8f;

__global__ __launch_bounds__(256, 2)
void edgeblock_gemm_fb(const float* __restrict__ nodes,
                       const float* __restrict__ edges,
                       const int*   __restrict__ recv,
                       const int*   __restrict__ send,
                       const float* __restrict__ W,
                       const float* __restrict__ bias,
                       float*       __restrict__ out,
                       int E)
{
    __shared__ __align__(16) unsigned short Asf[2][BM * SA];
    __shared__ __align__(16) unsigned short Bsf[2][BM * SA];
    const int tid = threadIdx.x;
    const int lane8 = tid & 7, h = tid >> 3;
    const int wave = tid >> 6, lane = tid & 63;
    const int quad = lane >> 4, l16 = lane & 15;
    const int wm = (wave >> 1) * 64, wn = (wave & 1) * 64;
    const long e0 = (long)blockIdx.x * BM;
    const float *baseE[4], *baseR[4], *baseS[4];
    #pragma unroll
    for (int i = 0; i < 4; ++i) {
        long e = e0 + h + 32 * i;
        if (e > (long)E - 1) e = (long)E - 1;
        baseE[i] = edges + e * 128L;
        baseR[i] = nodes + (long)recv[e] * 128;
        baseS[i] = nodes + (long)send[e] * 128;
    }
    float4 va[4], vb[4];
    auto loadChunk = [&](int c) {
        const int col = (c & 3) * 32;
        #pragma unroll
        for (int i = 0; i < 4; ++i) {
            const float* src = (c < 4) ? baseE[i] : (c < 8) ? baseR[i] : baseS[i];
            va[i] = *(const float4*)(src + col + lane8 * 4);
            vb[i] = *(const float4*)(W + (long)(h + 32 * i) * 384 + c * 32 + lane8 * 4);
        }
    };
    auto writeChunk = [&](int buf) {
        #pragma unroll
        for (int i = 0; i < 4; ++i) {
            uint2 pa, pb;
            pa.x = pack_bf16x2(va[i].x, va[i].y);
            pa.y = pack_bf16x2(va[i].z, va[i].w);
            pb.x = pack_bf16x2(vb[i].x, vb[i].y);
            pb.y = pack_bf16x2(vb[i].z, vb[i].w);
            *(uint2*)&Asf[buf][(h + 32 * i) * SA + lane8 * 4] = pa;
            *(uint2*)&Bsf[buf][(h + 32 * i) * SA + lane8 * 4] = pb;
        }
    };
    floatx4 acc[4][4] = {};
    loadChunk(0); writeChunk(0); __syncthreads();
    #pragma unroll
    for (int c = 0; c < NCH; ++c) {
        if (c + 1 < NCH) loadChunk(c + 1);
        const int buf = c & 1;
        bf16x8f af[4], bfr[4];
        #pragma unroll
        for (int mi = 0; mi < 4; ++mi)
            af[mi] = *(const bf16x8f*)&Asf[buf][(wm + mi * 16 + l16) * SA + quad * 8];
        #pragma unroll
        for (int ni = 0; ni < 4; ++ni)
            bfr[ni] = *(const bf16x8f*)&Bsf[buf][(wn + ni * 16 + l16) * SA + quad * 8];
        #pragma unroll
        for (int mi = 0; mi < 4; ++mi)
            #pragma unroll
            for (int ni = 0; ni < 4; ++ni)
                acc[mi][ni] = __builtin_amdgcn_mfma_f32_16x16x32_bf16(
                    af[mi], bfr[ni], acc[mi][ni], 0, 0, 0);
        if (c + 1 < NCH) writeChunk((c + 1) & 1);
        __syncthreads();
    }
    float bv[4];
    #pragma unroll
    for (int ni = 0; ni < 4; ++ni) bv[ni] = bias[wn + ni * 16 + l16];
    #pragma unroll
    for (int mi = 0; mi < 4; ++mi)
        #pragma unroll
        for (int r = 0; r < 4; ++r) {
            long row = e0 + wm + mi * 16 + quad * 4 + r;
            if (row < (long)E) {
                float* orow = out + row * 128L + wn + l16;
                #pragma unroll
                for (int ni = 0; ni < 4; ++ni)
                    orow[ni * 16] = acc[mi][ni][r] + bv[ni];
            }
        }
}

extern "C" void kernel_launch(void* const* d_in, const int* in_sizes, int n_in,
                              void* d_out, int out_size, void* d_ws, size_t ws_size,
                              hipStream_t stream) {
    const float* nodes = (const float*)d_in[0];
    const float* edges = (const float*)d_in[1];
    const int*   recv  = (const int*)d_in[2];
    const int*   send  = (const int*)d_in[3];
    const float* W     = (const float*)d_in[4];
    const float* bias  = (const float*)d_in[5];
    float* out = (float*)d_out;

    const int E = in_sizes[2];

    const size_t nodes_bytes = (size_t)in_sizes[0] * 2;          // bf16 nodes
    const size_t need = nodes_bytes + (size_t)in_sizes[4] * 2;   // + bf16 W
    if (ws_size < need) {
        const int gridf = (E + BM - 1) / BM;
        edgeblock_gemm_fb<<<gridf, 256, 0, stream>>>(nodes, edges, recv, send, W, bias, out, E);
        return;
    }

    unsigned short* nodes_bf = (unsigned short*)d_ws;
    unsigned short* w_bf     = (unsigned short*)((char*)d_ws + nodes_bytes);

    const int n4n = in_sizes[0] / 4;
    cvt_bf16<<<(n4n + 255) / 256, 256, 0, stream>>>(nodes, (unsigned int*)nodes_bf, n4n);
    const int n4w = in_sizes[4] / 4;
    cvt_bf16<<<(n4w + 255) / 256, 256, 0, stream>>>(W, (unsigned int*)w_bf, n4w);

    const int grid = (E + BM3 - 1) / BM3;
    edge_gemm_v3<<<grid, 256, 0, stream>>>(edges, recv, send, nodes_bf, w_bf, bias, out, E);
}